// Round 13
// baseline (212.633 us; speedup 1.0000x reference)
//
#include <hip/hip_runtime.h>
#include <hip/hip_bf16.h>

#define NVOX (64*64*64)      // 262144 = 2^18
#define NB32 (32*NVOX)       // 2^23 elements per image of 32-ch volume

typedef short s8v __attribute__((ext_vector_type(8)));   // 8 bf16 = 4 VGPR (MFMA A/B frag)
typedef float f4v __attribute__((ext_vector_type(4)));   // MFMA C/D frag

__device__ inline ushort bfb(float f) {
    __hip_bfloat16 h = __float2bfloat16(f);
    return *reinterpret_cast<ushort*>(&h);
}
__device__ inline float bf2f(ushort u) {
    unsigned x = (unsigned)u << 16;
    return __builtin_bit_cast(float, x);
}

// ---------------------------------------------------------------------------
// prep: conv weights [co][ci][tap] -> bf16 [tap][co][ci]; skip W -> bf16 [co][ci];
// zero stats
// ---------------------------------------------------------------------------
__global__ __launch_bounds__(256) void prep_kernel(
    const float* __restrict__ w1, const float* __restrict__ w2,
    const float* __restrict__ wsw,
    ushort* __restrict__ wB1, ushort* __restrict__ wB2,
    ushort* __restrict__ wsB, float* __restrict__ stats)
{
    if (blockIdx.x == 0 && threadIdx.x < 48) stats[threadIdx.x] = 0.f;
    int i = blockIdx.x * 256 + threadIdx.x;
    if (i < 1024) wsB[i] = bfb(wsw[i]);              // [co][ci]
    if (i < 32 * 32 * 27) {
        int co  = i / 864;            // 864 = 32*27
        int rem = i - co * 864;
        int ci  = rem / 27;
        int tap = rem - ci * 27;
        wB1[(tap * 32 + co) * 32 + ci] = bfb(w1[i]);
        wB2[(tap * 32 + co) * 32 + ci] = bfb(w2[i]);
    }
}

// ---------------------------------------------------------------------------
// fused: feat fp32 [c][vox] -> featB bf16 [vox][ci]
//        + skip 1x1 conv via MFMA -> skipB bf16 [vox][co] + GN3 stats.
// ---------------------------------------------------------------------------
__global__ __launch_bounds__(256) void tobf_skip_kernel(
    const float* __restrict__ in0, const float* __restrict__ in1,
    const ushort* __restrict__ wsB, const float* __restrict__ bsb,
    ushort* __restrict__ featB, ushort* __restrict__ skipB,
    float* __restrict__ stats)
{
    const int img = blockIdx.y;
    const float* __restrict__ in = img ? in1 : in0;
    const int t = threadIdx.x;
    const int lane = t & 63, wid = t >> 6;
    const int m = lane & 15, kc = lane >> 4;
    const int vb = blockIdx.x * 256 + wid * 64;   // wave's vox base

    ushort* __restrict__ fo = featB + (size_t)img * NVOX * 32;

    // load + convert + store featB; keep as B-frags (col=vox, k=ci)
    s8v bfrag[4];
#pragma unroll
    for (int nt = 0; nt < 4; ++nt) {
        const int vox = vb + nt * 16 + m;
        s8v pk;
#pragma unroll
        for (int j = 0; j < 8; ++j)
            pk[j] = (short)bfb(in[(kc * 8 + j) * NVOX + vox]);
        bfrag[nt] = pk;
        *reinterpret_cast<s8v*>(fo + (size_t)vox * 32 + kc * 8) = pk;
    }

    // skip 1x1 conv via MFMA (weights first -> D rows = co, cols = vox)
    const s8v* __restrict__ wv = reinterpret_cast<const s8v*>(wsB);
    const s8v a0 = wv[m * 4 + kc];          // A rows co 0..15
    const s8v a1 = wv[(m + 16) * 4 + kc];   // A rows co 16..31
    f4v acc[2][4] = {};
#pragma unroll
    for (int nt = 0; nt < 4; ++nt) {
        acc[0][nt] = __builtin_amdgcn_mfma_f32_16x16x32_bf16(a0, bfrag[nt], acc[0][nt], 0, 0, 0);
        acc[1][nt] = __builtin_amdgcn_mfma_f32_16x16x32_bf16(a1, bfrag[nt], acc[1][nt], 0, 0, 0);
    }

    // D: col = m = vox offset, row = kc*4+j (+16*mt) = co. Store [vox][co].
    ushort* __restrict__ sko = skipB + (size_t)img * NVOX * 32;
    float s0 = 0.f, q0 = 0.f, s1 = 0.f, q1 = 0.f;
#pragma unroll
    for (int mt = 0; mt < 2; ++mt) {
#pragma unroll
        for (int nt = 0; nt < 4; ++nt) {
            const f4v a = acc[mt][nt];
            ushort4 pk;
            float xs[4];
#pragma unroll
            for (int j = 0; j < 4; ++j) {
                const int co = mt * 16 + kc * 4 + j;
                xs[j] = a[j] + bsb[co];
            }
            pk.x = bfb(xs[0]); pk.y = bfb(xs[1]); pk.z = bfb(xs[2]); pk.w = bfb(xs[3]);
            *reinterpret_cast<ushort4*>(
                sko + (size_t)(vb + nt * 16 + m) * 32 + mt * 16 + kc * 4) = pk;
#pragma unroll
            for (int j = 0; j < 4; ++j) {
                if (mt == 0) { s0 += xs[j]; q0 += xs[j] * xs[j]; }
                else         { s1 += xs[j]; q1 += xs[j] * xs[j]; }
            }
        }
    }

    __shared__ float red[4][8];
    float v4[4] = {s0, q0, s1, q1};
#pragma unroll
    for (int k = 0; k < 4; ++k) {
        float x = v4[k];
        x += __shfl_xor(x, 1, 64);
        x += __shfl_xor(x, 2, 64);
        x += __shfl_xor(x, 4, 64);
        x += __shfl_xor(x, 8, 64);
        x += __shfl_xor(x, 16, 64);
        v4[k] = x;
    }
    if (lane == 0)  { red[wid][0] = v4[0]; red[wid][1] = v4[1]; red[wid][4] = v4[2]; red[wid][5] = v4[3]; }
    if (lane == 32) { red[wid][2] = v4[0]; red[wid][3] = v4[1]; red[wid][6] = v4[2]; red[wid][7] = v4[3]; }
    __syncthreads();
    if (t < 8) {
        atomicAdd(&stats[img * 24 + 16 + t],
                  red[0][t] + red[1][t] + red[2][t] + red[3][t]);
    }
}

// ---------------------------------------------------------------------------
// 3x3x3 conv 32->32 via bf16 MFMA implicit GEMM, zero pad, +bias, +GN stats.
// Round-11 structure (mfma(a, w), [co][vox] ushort4 epilogue) with SMALLER
// tile (4h,4w,16d): halo 6x6x18, LDS 41.6 KB -> 3 blocks/CU (3 waves/SIMD)
// for latency hiding. grid: (1024 = 16bh x 16bw x 4bd, 2 images).
// ---------------------------------------------------------------------------
__global__ __launch_bounds__(256) void conv3_mfma_kernel(
    const ushort* __restrict__ inB,
    const ushort* __restrict__ wB, const float* __restrict__ bias,
    ushort* __restrict__ outB, float* __restrict__ stats, int layer)
{
    __shared__ __align__(16) ushort tile[4 * 650 * 8];   // 41600 B
    __shared__ float red[4][8];

    const int img = blockIdx.y;
    const ushort* __restrict__ src = inB + (size_t)img * NVOX * 32;
    const int bx = blockIdx.x;
    const int bd = bx & 3, bw = (bx >> 2) & 15, bh = bx >> 6;
    const int t = threadIdx.x;

    // ---- stage halo tile: r = hw*18+dd (648 rows), 4 ci-quads of 16B ----
    const int gd0 = bd * 16 - 1, gh0 = bh * 4 - 1, gw0 = bw * 4 - 1;
    s8v* __restrict__ tvw = reinterpret_cast<s8v*>(tile);
    for (int u = t; u < 2592; u += 256) {       // 648*4
        const int r   = u >> 2;
        const int ciq = u & 3;
        const int hw = r / 18, dd = r - hw * 18;
        const int hh = hw / 6, ww = hw - hh * 6;
        const int gh = gh0 + hh, gw = gw0 + ww, gd = gd0 + dd;
        s8v val = {0, 0, 0, 0, 0, 0, 0, 0};
        if (((unsigned)gh < 64u) && ((unsigned)gw < 64u) && ((unsigned)gd < 64u))
            val = *reinterpret_cast<const s8v*>(
                src + (size_t)(((gh << 12) + (gw << 6) + gd) << 5) + (ciq << 3));
        tvw[ciq * 650 + r] = val;
    }
    __syncthreads();

    // ---- MFMA main loop (operand order mfma(a, w) — proven fast) ----
    const int lane = t & 63, wid = t >> 6;
    const int m = lane & 15, kc = lane >> 4;

    int pre8[4];   // A-frag row base per w'=i
#pragma unroll
    for (int i = 0; i < 4; ++i)
        pre8[i] = kc * 650 + (wid * 6 + i) * 18 + m;

    const int wlane = m * 4 + kc;   // B-frag s8v offset within a tap
    const s8v* __restrict__ tv = reinterpret_cast<const s8v*>(tile);
    const s8v* __restrict__ wv = reinterpret_cast<const s8v*>(wB);

    f4v acc[4][2] = {};
#pragma unroll
    for (int tap = 0; tap < 27; ++tap) {
        const int dh = tap / 9, dw = (tap / 3) % 3, dd = tap % 3;
        const int toff = (dh * 6 + dw) * 18 + dd;
        const s8v bf0 = wv[tap * 128 + wlane];        // co = m
        const s8v bf1 = wv[tap * 128 + 64 + wlane];   // co = m+16
#pragma unroll
        for (int i = 0; i < 4; ++i) {
            const s8v a = tv[pre8[i] + toff];
            acc[i][0] = __builtin_amdgcn_mfma_f32_16x16x32_bf16(a, bf0, acc[i][0], 0, 0, 0);
            acc[i][1] = __builtin_amdgcn_mfma_f32_16x16x32_bf16(a, bf1, acc[i][1], 0, 0, 0);
        }
    }

    // ---- epilogue: +bias, bf16 ushort4 store along d, GN stats (fp32) ----
    ushort* __restrict__ outi = outB + (size_t)img * NB32;
    const float b0 = bias[m], b1 = bias[m + 16];
    ushort* __restrict__ op0 = outi + (size_t)m * NVOX;           // co = m
    ushort* __restrict__ op1 = outi + (size_t)(m + 16) * NVOX;    // co = m+16
    const int vbase = ((bh * 4 + wid) << 12) + ((bw * 4) << 6) + bd * 16 + kc * 4;
    float gsum[2] = {0.f, 0.f}, gsq[2] = {0.f, 0.f};
#pragma unroll
    for (int i = 0; i < 4; ++i) {
        const int v = vbase + (i << 6);
#pragma unroll
        for (int nt = 0; nt < 2; ++nt) {
            const f4v a = acc[i][nt];
            const float bb = nt ? b1 : b0;
            const float x0 = a[0] + bb, x1 = a[1] + bb, x2 = a[2] + bb, x3 = a[3] + bb;
            ushort4 pk;
            pk.x = bfb(x0); pk.y = bfb(x1); pk.z = bfb(x2); pk.w = bfb(x3);
            *reinterpret_cast<ushort4*>((nt ? op1 : op0) + v) = pk;
            gsum[nt] += x0 + x1 + x2 + x3;
            gsq[nt]  += x0 * x0 + x1 * x1 + x2 * x2 + x3 * x3;
        }
    }

#pragma unroll
    for (int nt = 0; nt < 2; ++nt) {
        float s = gsum[nt], q = gsq[nt];
        s += __shfl_xor(s, 16, 64); q += __shfl_xor(q, 16, 64);
        s += __shfl_xor(s, 32, 64); q += __shfl_xor(q, 32, 64);
        s += __shfl_xor(s, 1, 64);  q += __shfl_xor(q, 1, 64);
        s += __shfl_xor(s, 2, 64);  q += __shfl_xor(q, 2, 64);
        s += __shfl_xor(s, 4, 64);  q += __shfl_xor(q, 4, 64);
        if (lane == 0) { const int g = nt * 2;     red[wid][g * 2] = s; red[wid][g * 2 + 1] = q; }
        if (lane == 8) { const int g = nt * 2 + 1; red[wid][g * 2] = s; red[wid][g * 2 + 1] = q; }
    }
    __syncthreads();
    if (t < 8) {
        atomicAdd(&stats[img * 24 + layer * 8 + t],
                  red[0][t] + red[1][t] + red[2][t] + red[3][t]);
    }
}

// ---------------------------------------------------------------------------
// GN1 apply + lrelu: cA bf16 [c][vox] -> bf16 [vox][ci]
// vectorized: each thread does 4 consecutive vox (ushort4 plane loads)
// grid: (256, 2 images)
// ---------------------------------------------------------------------------
__global__ __launch_bounds__(256) void gn_transpose_kernel(
    const ushort* __restrict__ cA, const float* __restrict__ stats,
    const float* __restrict__ gamma, const float* __restrict__ beta,
    ushort* __restrict__ outB)
{
    const int img = blockIdx.y;
    const ushort* __restrict__ in = cA + (size_t)img * NB32;
    ushort* __restrict__ op = outB + (size_t)img * NVOX * 32;
    const int v4 = (blockIdx.x * 256 + threadIdx.x) * 4;
    const float Minv = 1.f / (8.f * (float)NVOX);
    float mu[4], rs[4];
#pragma unroll
    for (int g = 0; g < 4; ++g) {
        const float s = stats[img * 24 + 2 * g], q = stats[img * 24 + 2 * g + 1];
        mu[g] = s * Minv;
        rs[g] = rsqrtf(q * Minv - mu[g] * mu[g] + 1e-5f);
    }
    s8v outv[4][4];   // [vox k][ci quad]
#pragma unroll
    for (int c = 0; c < 32; ++c) {
        const int g = c >> 3;
        const float sc = rs[g] * gamma[c];
        const float sh = beta[c] - mu[g] * sc;
        const ushort4 ld = *reinterpret_cast<const ushort4*>(in + (size_t)c * NVOX + v4);
        float y0 = bf2f(ld.x) * sc + sh; y0 = fmaxf(y0, 0.2f * y0);
        float y1 = bf2f(ld.y) * sc + sh; y1 = fmaxf(y1, 0.2f * y1);
        float y2 = bf2f(ld.z) * sc + sh; y2 = fmaxf(y2, 0.2f * y2);
        float y3 = bf2f(ld.w) * sc + sh; y3 = fmaxf(y3, 0.2f * y3);
        outv[0][c >> 3][c & 7] = (short)bfb(y0);
        outv[1][c >> 3][c & 7] = (short)bfb(y1);
        outv[2][c >> 3][c & 7] = (short)bfb(y2);
        outv[3][c >> 3][c & 7] = (short)bfb(y3);
    }
#pragma unroll
    for (int k = 0; k < 4; ++k)
#pragma unroll
    for (int cq = 0; cq < 4; ++cq)
        *reinterpret_cast<s8v*>(op + (size_t)(v4 + k) * 32 + cq * 8) = outv[k][cq];
}

// ---------------------------------------------------------------------------
// combine: GN2(cB [co][vox] strided) + GN3(skipB [vox][co] vectorized),
// residual add, lrelu, project to 16 emb ch -> embB bf16 [img][vox][16]
// ---------------------------------------------------------------------------
__global__ __launch_bounds__(256) void combine_kernel(
    const ushort* __restrict__ Bb, const ushort* __restrict__ Sk,
    const float* __restrict__ stats,
    const float* __restrict__ g2, const float* __restrict__ be2,
    const float* __restrict__ gs, const float* __restrict__ bes,
    const float* __restrict__ wp, const float* __restrict__ bp,
    ushort* __restrict__ embB)
{
    const int img = blockIdx.y;
    const int v   = blockIdx.x * 256 + threadIdx.x;
    const float Minv = 1.f / (8.f * (float)NVOX);
    float mu1[4], rs1[4], mu2[4], rs2[4];
#pragma unroll
    for (int g = 0; g < 4; ++g) {
        float s = stats[img * 24 + 8 + 2 * g], q = stats[img * 24 + 8 + 2 * g + 1];
        mu1[g] = s * Minv; rs1[g] = rsqrtf(q * Minv - mu1[g] * mu1[g] + 1e-5f);
        s = stats[img * 24 + 16 + 2 * g]; q = stats[img * 24 + 16 + 2 * g + 1];
        mu2[g] = s * Minv; rs2[g] = rsqrtf(q * Minv - mu2[g] * mu2[g] + 1e-5f);
    }
    const ushort* __restrict__ bb = Bb + (size_t)img * NB32;
    const ushort* __restrict__ sk = Sk + ((size_t)img * NVOX + v) * 32;
    float o[32];
#pragma unroll
    for (int cq = 0; cq < 4; ++cq) {
        const s8v sv8 = *reinterpret_cast<const s8v*>(sk + cq * 8);
#pragma unroll
        for (int j = 0; j < 8; ++j) {
            const int c = cq * 8 + j;
            const int g = c >> 3;
            const float hv = (bf2f(bb[c * NVOX + v]) - mu1[g]) * rs1[g] * g2[c] + be2[c];
            const float sv = (bf2f((ushort)sv8[j]) - mu2[g]) * rs2[g] * gs[c] + bes[c];
            const float tv = hv + sv;
            o[c] = tv >= 0.f ? tv : 0.2f * tv;
        }
    }
    ushort* __restrict__ eo = embB + ((size_t)img * NVOX + v) * 16;
#pragma unroll
    for (int eq = 0; eq < 2; ++eq) {
        s8v pk;
#pragma unroll
        for (int j = 0; j < 8; ++j) {
            const int e = eq * 8 + j;
            float s = bp[e];
#pragma unroll
            for (int c = 0; c < 32; ++c) s += wp[e * 32 + c] * o[c];
            pk[j] = (short)bfb(s);
        }
        *reinterpret_cast<s8v*>(eo + eq * 8) = pk;
    }
}

// ---------------------------------------------------------------------------
// attention: Q = embB[fixed][v][:], K gathered from embB[moving] (edge clamp),
// softmax over 27 neighbors, displacement = sum attn * offset (fp32 out)
// ---------------------------------------------------------------------------
__global__ __launch_bounds__(256) void attn_kernel(
    const ushort* __restrict__ embB, float* __restrict__ out)
{
    const int v = blockIdx.x * 256 + threadIdx.x;
    const int h = v >> 12, w = (v >> 6) & 63, d = v & 63;
    const ushort* __restrict__ Qp = embB + (size_t)v * 16;
    const ushort* __restrict__ Kp = embB + (size_t)NVOX * 16;
    float q[16];
    {
        const s8v q0 = *reinterpret_cast<const s8v*>(Qp);
        const s8v q1 = *reinterpret_cast<const s8v*>(Qp + 8);
#pragma unroll
        for (int j = 0; j < 8; ++j) { q[j] = bf2f((ushort)q0[j]); q[8 + j] = bf2f((ushort)q1[j]); }
    }
    float sc[27];
    float m = -1e30f;
#pragma unroll
    for (int ih = 0; ih < 3; ++ih)
#pragma unroll
    for (int iw = 0; iw < 3; ++iw)
#pragma unroll
    for (int id = 0; id < 3; ++id) {
        int hh = h + ih - 1; hh = hh < 0 ? 0 : (hh > 63 ? 63 : hh);
        int ww = w + iw - 1; ww = ww < 0 ? 0 : (ww > 63 ? 63 : ww);
        int dd = d + id - 1; dd = dd < 0 ? 0 : (dd > 63 ? 63 : dd);
        const ushort* __restrict__ kp = Kp + (size_t)((hh << 12) + (ww << 6) + dd) * 16;
        const s8v k0 = *reinterpret_cast<const s8v*>(kp);
        const s8v k1 = *reinterpret_cast<const s8v*>(kp + 8);
        float s = 0.f;
#pragma unroll
        for (int j = 0; j < 8; ++j)
            s += q[j] * bf2f((ushort)k0[j]) + q[8 + j] * bf2f((ushort)k1[j]);
        s *= 0.25f;   // / sqrt(16)
        sc[(ih * 3 + iw) * 3 + id] = s;
        m = fmaxf(m, s);
    }
    float den = 0.f;
#pragma unroll
    for (int p = 0; p < 27; ++p) { sc[p] = __expf(sc[p] - m); den += sc[p]; }
    const float inv = 1.f / den;
    float r0 = 0.f, r1 = 0.f, r2 = 0.f;
#pragma unroll
    for (int ih = 0; ih < 3; ++ih)
#pragma unroll
    for (int iw = 0; iw < 3; ++iw)
#pragma unroll
    for (int id = 0; id < 3; ++id) {
        const float a = sc[(ih * 3 + iw) * 3 + id] * inv;
        r0 += a * (float)(ih - 1);
        r1 += a * (float)(iw - 1);
        r2 += a * (float)(id - 1);
    }
    out[v]            = r0;
    out[NVOX + v]     = r1;
    out[2 * NVOX + v] = r2;
}

// ---------------------------------------------------------------------------
extern "C" void kernel_launch(void* const* d_in, const int* in_sizes, int n_in,
                              void* d_out, int out_size, void* d_ws, size_t ws_size,
                              hipStream_t stream)
{
    (void)in_sizes; (void)n_in; (void)out_size; (void)ws_size;
    const float* feat_moving = (const float*)d_in[0];
    const float* feat_fixed  = (const float*)d_in[1];
    const float* w1  = (const float*)d_in[2];
    const float* b1  = (const float*)d_in[3];
    const float* g1  = (const float*)d_in[4];
    const float* be1 = (const float*)d_in[5];
    const float* w2  = (const float*)d_in[6];
    const float* b2  = (const float*)d_in[7];
    const float* g2  = (const float*)d_in[8];
    const float* be2 = (const float*)d_in[9];
    const float* wsw = (const float*)d_in[10];
    const float* bs  = (const float*)d_in[11];
    const float* gs  = (const float*)d_in[12];
    const float* bes = (const float*)d_in[13];
    const float* wp  = (const float*)d_in[14];
    const float* bp  = (const float*)d_in[15];

    // workspace by lifetime (MiB offsets), max ~160.1 MiB:
    //   featB [0,32)   bf16 [vox][ci]   live tobf_skip..conv1 ; embB aliases
    //   cA    [32,64)  bf16 [co][vox]   live conv1..gn_t
    //   AB    [64,96)  bf16 [vox][ci]   live gn_t..conv2
    //   cB    [96,128) bf16 [co][vox]   live conv2..combine
    //   skipB [128,160)bf16 [vox][co]   live tobf_skip..combine
    //   embB = featB region, bf16 [img][vox][16], live combine..attn
    char* base = (char*)d_ws;
    ushort* featB = (ushort*)base;
    ushort* cA    = (ushort*)(base + (32ull << 20));
    ushort* AB    = (ushort*)(base + (64ull << 20));
    ushort* cB    = (ushort*)(base + (96ull << 20));
    ushort* skipB = (ushort*)(base + (128ull << 20));
    ushort* embB  = (ushort*)base;
    float*  stats = (float*)(base + (160ull << 20));
    ushort* wB1   = (ushort*)(stats + 64);
    ushort* wB2   = wB1 + 27648;
    ushort* wsB   = wB2 + 27648;

    prep_kernel<<<108, 256, 0, stream>>>(w1, w2, wsw, wB1, wB2, wsB, stats);
    tobf_skip_kernel<<<dim3(1024, 2), 256, 0, stream>>>(feat_fixed, feat_moving, wsB, bs,
                                                        featB, skipB, stats);
    conv3_mfma_kernel<<<dim3(1024, 2), 256, 0, stream>>>(featB, wB1, b1, cA, stats, 0);
    gn_transpose_kernel<<<dim3(256, 2), 256, 0, stream>>>(cA, stats, g1, be1, AB);
    conv3_mfma_kernel<<<dim3(1024, 2), 256, 0, stream>>>(AB, wB2, b2, cB, stats, 1);
    combine_kernel<<<dim3(1024, 2), 256, 0, stream>>>(cB, skipB, stats, g2, be2, gs, bes,
                                                      wp, bp, embB);
    attn_kernel<<<1024, 256, 0, stream>>>(embB, (float*)d_out);
}

// Round 14
// 175.907 us; speedup vs baseline: 1.2088x; 1.2088x over previous
//
#include <hip/hip_runtime.h>
#include <hip/hip_bf16.h>

#define NVOX (64*64*64)      // 262144 = 2^18
#define NB32 (32*NVOX)       // 2^23 elements per image of 32-ch volume

typedef short s8v __attribute__((ext_vector_type(8)));   // 8 bf16 = 4 VGPR (MFMA A/B frag)
typedef float f4v __attribute__((ext_vector_type(4)));   // MFMA C/D frag

__device__ inline ushort bfb(float f) {
    __hip_bfloat16 h = __float2bfloat16(f);
    return *reinterpret_cast<ushort*>(&h);
}
__device__ inline float bf2f(ushort u) {
    unsigned x = (unsigned)u << 16;
    return __builtin_bit_cast(float, x);
}

// ---------------------------------------------------------------------------
// prep: conv weights [co][ci][tap] -> bf16 [tap][co][ci]; skip W -> bf16 [co][ci];
// zero stats
// ---------------------------------------------------------------------------
__global__ __launch_bounds__(256) void prep_kernel(
    const float* __restrict__ w1, const float* __restrict__ w2,
    const float* __restrict__ wsw,
    ushort* __restrict__ wB1, ushort* __restrict__ wB2,
    ushort* __restrict__ wsB, float* __restrict__ stats)
{
    if (blockIdx.x == 0 && threadIdx.x < 48) stats[threadIdx.x] = 0.f;
    int i = blockIdx.x * 256 + threadIdx.x;
    if (i < 1024) wsB[i] = bfb(wsw[i]);              // [co][ci]
    if (i < 32 * 32 * 27) {
        int co  = i / 864;            // 864 = 32*27
        int rem = i - co * 864;
        int ci  = rem / 27;
        int tap = rem - ci * 27;
        wB1[(tap * 32 + co) * 32 + ci] = bfb(w1[i]);
        wB2[(tap * 32 + co) * 32 + ci] = bfb(w2[i]);
    }
}

// ---------------------------------------------------------------------------
// fused: feat fp32 [c][vox] -> featB bf16 [vox][ci]
//        + skip 1x1 conv via MFMA -> skipB bf16 [vox][co] + GN3 stats.
// Wave covers 128 vox (nt=0..7) for 2x load ILP. grid: (512, 2 images)
// ---------------------------------------------------------------------------
__global__ __launch_bounds__(256) void tobf_skip_kernel(
    const float* __restrict__ in0, const float* __restrict__ in1,
    const ushort* __restrict__ wsB, const float* __restrict__ bsb,
    ushort* __restrict__ featB, ushort* __restrict__ skipB,
    float* __restrict__ stats)
{
    const int img = blockIdx.y;
    const float* __restrict__ in = img ? in1 : in0;
    const int t = threadIdx.x;
    const int lane = t & 63, wid = t >> 6;
    const int m = lane & 15, kc = lane >> 4;
    const int vb = blockIdx.x * 512 + wid * 128;   // wave's vox base

    ushort* __restrict__ fo = featB + (size_t)img * NVOX * 32;

    // load + convert + store featB; keep as B-frags (col=vox, k=ci)
    s8v bfrag[8];
#pragma unroll
    for (int nt = 0; nt < 8; ++nt) {
        const int vox = vb + nt * 16 + m;
        s8v pk;
#pragma unroll
        for (int j = 0; j < 8; ++j)
            pk[j] = (short)bfb(in[(kc * 8 + j) * NVOX + vox]);
        bfrag[nt] = pk;
        *reinterpret_cast<s8v*>(fo + (size_t)vox * 32 + kc * 8) = pk;
    }

    // skip 1x1 conv via MFMA (weights first -> D rows = co, cols = vox)
    const s8v* __restrict__ wv = reinterpret_cast<const s8v*>(wsB);
    const s8v a0 = wv[m * 4 + kc];          // A rows co 0..15
    const s8v a1 = wv[(m + 16) * 4 + kc];   // A rows co 16..31
    f4v acc[2][8] = {};
#pragma unroll
    for (int nt = 0; nt < 8; ++nt) {
        acc[0][nt] = __builtin_amdgcn_mfma_f32_16x16x32_bf16(a0, bfrag[nt], acc[0][nt], 0, 0, 0);
        acc[1][nt] = __builtin_amdgcn_mfma_f32_16x16x32_bf16(a1, bfrag[nt], acc[1][nt], 0, 0, 0);
    }

    // D: col = m = vox offset, row = kc*4+j (+16*mt) = co. Store [vox][co].
    ushort* __restrict__ sko = skipB + (size_t)img * NVOX * 32;
    float s0 = 0.f, q0 = 0.f, s1 = 0.f, q1 = 0.f;
#pragma unroll
    for (int mt = 0; mt < 2; ++mt) {
#pragma unroll
        for (int nt = 0; nt < 8; ++nt) {
            const f4v a = acc[mt][nt];
            ushort4 pk;
            float xs[4];
#pragma unroll
            for (int j = 0; j < 4; ++j) {
                const int co = mt * 16 + kc * 4 + j;
                xs[j] = a[j] + bsb[co];
            }
            pk.x = bfb(xs[0]); pk.y = bfb(xs[1]); pk.z = bfb(xs[2]); pk.w = bfb(xs[3]);
            *reinterpret_cast<ushort4*>(
                sko + (size_t)(vb + nt * 16 + m) * 32 + mt * 16 + kc * 4) = pk;
#pragma unroll
            for (int j = 0; j < 4; ++j) {
                if (mt == 0) { s0 += xs[j]; q0 += xs[j] * xs[j]; }
                else         { s1 += xs[j]; q1 += xs[j] * xs[j]; }
            }
        }
    }

    __shared__ float red[4][8];
    float v4[4] = {s0, q0, s1, q1};
#pragma unroll
    for (int k = 0; k < 4; ++k) {
        float x = v4[k];
        x += __shfl_xor(x, 1, 64);
        x += __shfl_xor(x, 2, 64);
        x += __shfl_xor(x, 4, 64);
        x += __shfl_xor(x, 8, 64);
        x += __shfl_xor(x, 16, 64);
        v4[k] = x;
    }
    if (lane == 0)  { red[wid][0] = v4[0]; red[wid][1] = v4[1]; red[wid][4] = v4[2]; red[wid][5] = v4[3]; }
    if (lane == 32) { red[wid][2] = v4[0]; red[wid][3] = v4[1]; red[wid][6] = v4[2]; red[wid][7] = v4[3]; }
    __syncthreads();
    if (t < 8) {
        atomicAdd(&stats[img * 24 + 16 + t],
                  red[0][t] + red[1][t] + red[2][t] + red[3][t]);
    }
}

// ---------------------------------------------------------------------------
// 3x3x3 conv 32->32 via bf16 MFMA implicit GEMM, zero pad, +bias, +GN stats.
// EXACT round-11 structure (measured 49us): input bf16 [vox][ci], output bf16
// [co][vox] (ushort4 along d), mfma(a, w). Block: 256 thr (4 waves),
// tile (4h,4w,32d). LDS: 4 ci-quad planes, stride 1226 s8v (78.4 KB).
// grid: (512 = 16bh x 16bw x 2bd, 2 images)
// ---------------------------------------------------------------------------
__global__ __launch_bounds__(256) void conv3_mfma_kernel(
    const ushort* __restrict__ inB,
    const ushort* __restrict__ wB, const float* __restrict__ bias,
    ushort* __restrict__ outB, float* __restrict__ stats, int layer)
{
    __shared__ __align__(16) ushort tile[4 * 1226 * 8];   // 78464 B
    __shared__ float red[4][8];

    const int img = blockIdx.y;
    const ushort* __restrict__ src = inB + (size_t)img * NVOX * 32;
    const int bx = blockIdx.x;
    const int bd = bx & 1, bw = (bx >> 1) & 15, bh = bx >> 5;
    const int t = threadIdx.x;

    // ---- stage halo tile: r = hw*34+dd (1224 rows), 4 ci-quads of 16B ----
    const int gd0 = bd * 32 - 1, gh0 = bh * 4 - 1, gw0 = bw * 4 - 1;
    s8v* __restrict__ tvw = reinterpret_cast<s8v*>(tile);
    for (int u = t; u < 4896; u += 256) {       // 1224*4
        const int r   = u >> 2;
        const int ciq = u & 3;
        const int hw = r / 34, dd = r - hw * 34;
        const int hh = hw / 6, ww = hw - hh * 6;
        const int gh = gh0 + hh, gw = gw0 + ww, gd = gd0 + dd;
        s8v val = {0, 0, 0, 0, 0, 0, 0, 0};
        if (((unsigned)gh < 64u) && ((unsigned)gw < 64u) && ((unsigned)gd < 64u))
            val = *reinterpret_cast<const s8v*>(
                src + (size_t)(((gh << 12) + (gw << 6) + gd) << 5) + (ciq << 3));
        tvw[ciq * 1226 + r] = val;
    }
    __syncthreads();

    // ---- MFMA main loop ----
    const int lane = t & 63, wid = t >> 6;
    const int m = lane & 15, kc = lane >> 4;

    int pre8[4][2];   // A-frag row base per (w'=i, d-subtile dt)
#pragma unroll
    for (int i = 0; i < 4; ++i)
#pragma unroll
    for (int dt = 0; dt < 2; ++dt)
        pre8[i][dt] = kc * 1226 + (wid * 6 + i) * 34 + dt * 16 + m;

    const int wlane = m * 4 + kc;   // B-frag s8v offset within a tap
    const s8v* __restrict__ tv = reinterpret_cast<const s8v*>(tile);
    const s8v* __restrict__ wv = reinterpret_cast<const s8v*>(wB);

    f4v acc[4][2][2] = {};
#pragma unroll
    for (int tap = 0; tap < 27; ++tap) {
        const int dh = tap / 9, dw = (tap / 3) % 3, dd = tap % 3;
        const int toff = (dh * 6 + dw) * 34 + dd;
        const s8v bf0 = wv[tap * 128 + wlane];        // co = m
        const s8v bf1 = wv[tap * 128 + 64 + wlane];   // co = m+16
#pragma unroll
        for (int i = 0; i < 4; ++i)
#pragma unroll
        for (int dt = 0; dt < 2; ++dt) {
            const s8v a = tv[pre8[i][dt] + toff];
            acc[i][dt][0] = __builtin_amdgcn_mfma_f32_16x16x32_bf16(a, bf0, acc[i][dt][0], 0, 0, 0);
            acc[i][dt][1] = __builtin_amdgcn_mfma_f32_16x16x32_bf16(a, bf1, acc[i][dt][1], 0, 0, 0);
        }
    }

    // ---- epilogue: +bias, bf16 ushort4 store along d, GN stats (fp32) ----
    ushort* __restrict__ outi = outB + (size_t)img * NB32;
    const float b0 = bias[m], b1 = bias[m + 16];
    ushort* __restrict__ op0 = outi + (size_t)m * NVOX;           // co = m
    ushort* __restrict__ op1 = outi + (size_t)(m + 16) * NVOX;    // co = m+16
    const int vbase = ((bh * 4 + wid) << 12) + ((bw * 4) << 6) + bd * 32 + kc * 4;
    float gsum[2] = {0.f, 0.f}, gsq[2] = {0.f, 0.f};
#pragma unroll
    for (int i = 0; i < 4; ++i) {
#pragma unroll
        for (int dt = 0; dt < 2; ++dt) {
            const int v = vbase + (i << 6) + dt * 16;
#pragma unroll
            for (int nt = 0; nt < 2; ++nt) {
                const f4v a = acc[i][dt][nt];
                const float bb = nt ? b1 : b0;
                const float x0 = a[0] + bb, x1 = a[1] + bb, x2 = a[2] + bb, x3 = a[3] + bb;
                ushort4 pk;
                pk.x = bfb(x0); pk.y = bfb(x1); pk.z = bfb(x2); pk.w = bfb(x3);
                *reinterpret_cast<ushort4*>((nt ? op1 : op0) + v) = pk;
                gsum[nt] += x0 + x1 + x2 + x3;
                gsq[nt]  += x0 * x0 + x1 * x1 + x2 * x2 + x3 * x3;
            }
        }
    }

#pragma unroll
    for (int nt = 0; nt < 2; ++nt) {
        float s = gsum[nt], q = gsq[nt];
        s += __shfl_xor(s, 16, 64); q += __shfl_xor(q, 16, 64);
        s += __shfl_xor(s, 32, 64); q += __shfl_xor(q, 32, 64);
        s += __shfl_xor(s, 1, 64);  q += __shfl_xor(q, 1, 64);
        s += __shfl_xor(s, 2, 64);  q += __shfl_xor(q, 2, 64);
        s += __shfl_xor(s, 4, 64);  q += __shfl_xor(q, 4, 64);
        if (lane == 0) { const int g = nt * 2;     red[wid][g * 2] = s; red[wid][g * 2 + 1] = q; }
        if (lane == 8) { const int g = nt * 2 + 1; red[wid][g * 2] = s; red[wid][g * 2 + 1] = q; }
    }
    __syncthreads();
    if (t < 8) {
        atomicAdd(&stats[img * 24 + layer * 8 + t],
                  red[0][t] + red[1][t] + red[2][t] + red[3][t]);
    }
}

// ---------------------------------------------------------------------------
// GN1 apply + lrelu: cA bf16 [c][vox] -> bf16 [vox][ci]
// vectorized: each thread does 4 consecutive vox (ushort4 plane loads)
// grid: (256, 2 images)
// ---------------------------------------------------------------------------
__global__ __launch_bounds__(256) void gn_transpose_kernel(
    const ushort* __restrict__ cA, const float* __restrict__ stats,
    const float* __restrict__ gamma, const float* __restrict__ beta,
    ushort* __restrict__ outB)
{
    const int img = blockIdx.y;
    const ushort* __restrict__ in = cA + (size_t)img * NB32;
    ushort* __restrict__ op = outB + (size_t)img * NVOX * 32;
    const int v4 = (blockIdx.x * 256 + threadIdx.x) * 4;
    const float Minv = 1.f / (8.f * (float)NVOX);
    float mu[4], rs[4];
#pragma unroll
    for (int g = 0; g < 4; ++g) {
        const float s = stats[img * 24 + 2 * g], q = stats[img * 24 + 2 * g + 1];
        mu[g] = s * Minv;
        rs[g] = rsqrtf(q * Minv - mu[g] * mu[g] + 1e-5f);
    }
    s8v outv[4][4];   // [vox k][ci quad]
#pragma unroll
    for (int c = 0; c < 32; ++c) {
        const int g = c >> 3;
        const float sc = rs[g] * gamma[c];
        const float sh = beta[c] - mu[g] * sc;
        const ushort4 ld = *reinterpret_cast<const ushort4*>(in + (size_t)c * NVOX + v4);
        float y0 = bf2f(ld.x) * sc + sh; y0 = fmaxf(y0, 0.2f * y0);
        float y1 = bf2f(ld.y) * sc + sh; y1 = fmaxf(y1, 0.2f * y1);
        float y2 = bf2f(ld.z) * sc + sh; y2 = fmaxf(y2, 0.2f * y2);
        float y3 = bf2f(ld.w) * sc + sh; y3 = fmaxf(y3, 0.2f * y3);
        outv[0][c >> 3][c & 7] = (short)bfb(y0);
        outv[1][c >> 3][c & 7] = (short)bfb(y1);
        outv[2][c >> 3][c & 7] = (short)bfb(y2);
        outv[3][c >> 3][c & 7] = (short)bfb(y3);
    }
#pragma unroll
    for (int k = 0; k < 4; ++k)
#pragma unroll
    for (int cq = 0; cq < 4; ++cq)
        *reinterpret_cast<s8v*>(op + (size_t)(v4 + k) * 32 + cq * 8) = outv[k][cq];
}

// ---------------------------------------------------------------------------
// combine: GN2(cB [co][vox] strided) + GN3(skipB [vox][co] vectorized),
// residual add, lrelu, project to 16 emb ch -> embB bf16 [img][vox][16]
// ---------------------------------------------------------------------------
__global__ __launch_bounds__(256) void combine_kernel(
    const ushort* __restrict__ Bb, const ushort* __restrict__ Sk,
    const float* __restrict__ stats,
    const float* __restrict__ g2, const float* __restrict__ be2,
    const float* __restrict__ gs, const float* __restrict__ bes,
    const float* __restrict__ wp, const float* __restrict__ bp,
    ushort* __restrict__ embB)
{
    const int img = blockIdx.y;
    const int v   = blockIdx.x * 256 + threadIdx.x;
    const float Minv = 1.f / (8.f * (float)NVOX);
    float mu1[4], rs1[4], mu2[4], rs2[4];
#pragma unroll
    for (int g = 0; g < 4; ++g) {
        float s = stats[img * 24 + 8 + 2 * g], q = stats[img * 24 + 8 + 2 * g + 1];
        mu1[g] = s * Minv; rs1[g] = rsqrtf(q * Minv - mu1[g] * mu1[g] + 1e-5f);
        s = stats[img * 24 + 16 + 2 * g]; q = stats[img * 24 + 16 + 2 * g + 1];
        mu2[g] = s * Minv; rs2[g] = rsqrtf(q * Minv - mu2[g] * mu2[g] + 1e-5f);
    }
    const ushort* __restrict__ bb = Bb + (size_t)img * NB32;
    const ushort* __restrict__ sk = Sk + ((size_t)img * NVOX + v) * 32;
    float o[32];
#pragma unroll
    for (int cq = 0; cq < 4; ++cq) {
        const s8v sv8 = *reinterpret_cast<const s8v*>(sk + cq * 8);
#pragma unroll
        for (int j = 0; j < 8; ++j) {
            const int c = cq * 8 + j;
            const int g = c >> 3;
            const float hv = (bf2f(bb[c * NVOX + v]) - mu1[g]) * rs1[g] * g2[c] + be2[c];
            const float sv = (bf2f((ushort)sv8[j]) - mu2[g]) * rs2[g] * gs[c] + bes[c];
            const float tv = hv + sv;
            o[c] = tv >= 0.f ? tv : 0.2f * tv;
        }
    }
    ushort* __restrict__ eo = embB + ((size_t)img * NVOX + v) * 16;
#pragma unroll
    for (int eq = 0; eq < 2; ++eq) {
        s8v pk;
#pragma unroll
        for (int j = 0; j < 8; ++j) {
            const int e = eq * 8 + j;
            float s = bp[e];
#pragma unroll
            for (int c = 0; c < 32; ++c) s += wp[e * 32 + c] * o[c];
            pk[j] = (short)bfb(s);
        }
        *reinterpret_cast<s8v*>(eo + eq * 8) = pk;
    }
}

// ---------------------------------------------------------------------------
// attention: Q = embB[fixed][v][:], K gathered from embB[moving] (edge clamp),
// softmax over 27 neighbors, displacement = sum attn * offset (fp32 out)
// ---------------------------------------------------------------------------
__global__ __launch_bounds__(256) void attn_kernel(
    const ushort* __restrict__ embB, float* __restrict__ out)
{
    const int v = blockIdx.x * 256 + threadIdx.x;
    const int h = v >> 12, w = (v >> 6) & 63, d = v & 63;
    const ushort* __restrict__ Qp = embB + (size_t)v * 16;
    const ushort* __restrict__ Kp = embB + (size_t)NVOX * 16;
    float q[16];
    {
        const s8v q0 = *reinterpret_cast<const s8v*>(Qp);
        const s8v q1 = *reinterpret_cast<const s8v*>(Qp + 8);
#pragma unroll
        for (int j = 0; j < 8; ++j) { q[j] = bf2f((ushort)q0[j]); q[8 + j] = bf2f((ushort)q1[j]); }
    }
    float sc[27];
    float m = -1e30f;
#pragma unroll
    for (int ih = 0; ih < 3; ++ih)
#pragma unroll
    for (int iw = 0; iw < 3; ++iw)
#pragma unroll
    for (int id = 0; id < 3; ++id) {
        int hh = h + ih - 1; hh = hh < 0 ? 0 : (hh > 63 ? 63 : hh);
        int ww = w + iw - 1; ww = ww < 0 ? 0 : (ww > 63 ? 63 : ww);
        int dd = d + id - 1; dd = dd < 0 ? 0 : (dd > 63 ? 63 : dd);
        const ushort* __restrict__ kp = Kp + (size_t)((hh << 12) + (ww << 6) + dd) * 16;
        const s8v k0 = *reinterpret_cast<const s8v*>(kp);
        const s8v k1 = *reinterpret_cast<const s8v*>(kp + 8);
        float s = 0.f;
#pragma unroll
        for (int j = 0; j < 8; ++j)
            s += q[j] * bf2f((ushort)k0[j]) + q[8 + j] * bf2f((ushort)k1[j]);
        s *= 0.25f;   // / sqrt(16)
        sc[(ih * 3 + iw) * 3 + id] = s;
        m = fmaxf(m, s);
    }
    float den = 0.f;
#pragma unroll
    for (int p = 0; p < 27; ++p) { sc[p] = __expf(sc[p] - m); den += sc[p]; }
    const float inv = 1.f / den;
    float r0 = 0.f, r1 = 0.f, r2 = 0.f;
#pragma unroll
    for (int ih = 0; ih < 3; ++ih)
#pragma unroll
    for (int iw = 0; iw < 3; ++iw)
#pragma unroll
    for (int id = 0; id < 3; ++id) {
        const float a = sc[(ih * 3 + iw) * 3 + id] * inv;
        r0 += a * (float)(ih - 1);
        r1 += a * (float)(iw - 1);
        r2 += a * (float)(id - 1);
    }
    out[v]            = r0;
    out[NVOX + v]     = r1;
    out[2 * NVOX + v] = r2;
}

// ---------------------------------------------------------------------------
extern "C" void kernel_launch(void* const* d_in, const int* in_sizes, int n_in,
                              void* d_out, int out_size, void* d_ws, size_t ws_size,
                              hipStream_t stream)
{
    (void)in_sizes; (void)n_in; (void)out_size; (void)ws_size;
    const float* feat_moving = (const float*)d_in[0];
    const float* feat_fixed  = (const float*)d_in[1];
    const float* w1  = (const float*)d_in[2];
    const float* b1  = (const float*)d_in[3];
    const float* g1  = (const float*)d_in[4];
    const float* be1 = (const float*)d_in[5];
    const float* w2  = (const float*)d_in[6];
    const float* b2  = (const float*)d_in[7];
    const float* g2  = (const float*)d_in[8];
    const float* be2 = (const float*)d_in[9];
    const float* wsw = (const float*)d_in[10];
    const float* bs  = (const float*)d_in[11];
    const float* gs  = (const float*)d_in[12];
    const float* bes = (const float*)d_in[13];
    const float* wp  = (const float*)d_in[14];
    const float* bp  = (const float*)d_in[15];

    // workspace by lifetime (MiB offsets), max ~160.1 MiB:
    //   featB [0,32)   bf16 [vox][ci]   live tobf_skip..conv1 ; embB aliases
    //   cA    [32,64)  bf16 [co][vox]   live conv1..gn_t
    //   AB    [64,96)  bf16 [vox][ci]   live gn_t..conv2
    //   cB    [96,128) bf16 [co][vox]   live conv2..combine
    //   skipB [128,160)bf16 [vox][co]   live tobf_skip..combine
    //   embB = featB region, bf16 [img][vox][16], live combine..attn
    char* base = (char*)d_ws;
    ushort* featB = (ushort*)base;
    ushort* cA    = (ushort*)(base + (32ull << 20));
    ushort* AB    = (ushort*)(base + (64ull << 20));
    ushort* cB    = (ushort*)(base + (96ull << 20));
    ushort* skipB = (ushort*)(base + (128ull << 20));
    ushort* embB  = (ushort*)base;
    float*  stats = (float*)(base + (160ull << 20));
    ushort* wB1   = (ushort*)(stats + 64);
    ushort* wB2   = wB1 + 27648;
    ushort* wsB   = wB2 + 27648;

    prep_kernel<<<108, 256, 0, stream>>>(w1, w2, wsw, wB1, wB2, wsB, stats);
    tobf_skip_kernel<<<dim3(512, 2), 256, 0, stream>>>(feat_fixed, feat_moving, wsB, bs,
                                                       featB, skipB, stats);
    conv3_mfma_kernel<<<dim3(512, 2), 256, 0, stream>>>(featB, wB1, b1, cA, stats, 0);
    gn_transpose_kernel<<<dim3(256, 2), 256, 0, stream>>>(cA, stats, g1, be1, AB);
    conv3_mfma_kernel<<<dim3(512, 2), 256, 0, stream>>>(AB, wB2, b2, cB, stats, 1);
    combine_kernel<<<dim3(1024, 2), 256, 0, stream>>>(cB, skipB, stats, g2, be2, gs, bes,
                                                      wp, bp, embB);
    attn_kernel<<<1024, 256, 0, stream>>>(embB, (float*)d_out);
}

// Round 15
// 170.957 us; speedup vs baseline: 1.2438x; 1.0290x over previous
//
#include <hip/hip_runtime.h>
#include <hip/hip_bf16.h>

#define NVOX (64*64*64)      // 262144 = 2^18
#define NB32 (32*NVOX)       // 2^23 elements per image of 32-ch volume

typedef short s8v __attribute__((ext_vector_type(8)));   // 8 bf16 = 4 VGPR (MFMA A/B frag)
typedef float f4v __attribute__((ext_vector_type(4)));   // MFMA C/D frag

__device__ inline ushort bfb(float f) {
    __hip_bfloat16 h = __float2bfloat16(f);
    return *reinterpret_cast<ushort*>(&h);
}
__device__ inline float bf2f(ushort u) {
    unsigned x = (unsigned)u << 16;
    return __builtin_bit_cast(float, x);
}

// ---------------------------------------------------------------------------
// prep: conv weights [co][ci][tap] -> bf16 [tap][co][ci]; skip W -> bf16 [co][ci];
// zero stats[0..63] (stats+48 doubles as the 64B zero page for conv staging)
// ---------------------------------------------------------------------------
__global__ __launch_bounds__(256) void prep_kernel(
    const float* __restrict__ w1, const float* __restrict__ w2,
    const float* __restrict__ wsw,
    ushort* __restrict__ wB1, ushort* __restrict__ wB2,
    ushort* __restrict__ wsB, float* __restrict__ stats)
{
    if (blockIdx.x == 0 && threadIdx.x < 64) stats[threadIdx.x] = 0.f;
    int i = blockIdx.x * 256 + threadIdx.x;
    if (i < 1024) wsB[i] = bfb(wsw[i]);              // [co][ci]
    if (i < 32 * 32 * 27) {
        int co  = i / 864;            // 864 = 32*27
        int rem = i - co * 864;
        int ci  = rem / 27;
        int tap = rem - ci * 27;
        wB1[(tap * 32 + co) * 32 + ci] = bfb(w1[i]);
        wB2[(tap * 32 + co) * 32 + ci] = bfb(w2[i]);
    }
}

// ---------------------------------------------------------------------------
// fused: feat fp32 [c][vox] -> featB bf16 [vox][ci]
//        + skip 1x1 conv via MFMA -> skipB bf16 [vox][co] + GN3 stats.
// Wave covers 128 vox (nt=0..7) for 2x load ILP. grid: (512, 2 images)
// ---------------------------------------------------------------------------
__global__ __launch_bounds__(256) void tobf_skip_kernel(
    const float* __restrict__ in0, const float* __restrict__ in1,
    const ushort* __restrict__ wsB, const float* __restrict__ bsb,
    ushort* __restrict__ featB, ushort* __restrict__ skipB,
    float* __restrict__ stats)
{
    const int img = blockIdx.y;
    const float* __restrict__ in = img ? in1 : in0;
    const int t = threadIdx.x;
    const int lane = t & 63, wid = t >> 6;
    const int m = lane & 15, kc = lane >> 4;
    const int vb = blockIdx.x * 512 + wid * 128;   // wave's vox base

    ushort* __restrict__ fo = featB + (size_t)img * NVOX * 32;

    // load + convert + store featB; keep as B-frags (col=vox, k=ci)
    s8v bfrag[8];
#pragma unroll
    for (int nt = 0; nt < 8; ++nt) {
        const int vox = vb + nt * 16 + m;
        s8v pk;
#pragma unroll
        for (int j = 0; j < 8; ++j)
            pk[j] = (short)bfb(in[(kc * 8 + j) * NVOX + vox]);
        bfrag[nt] = pk;
        *reinterpret_cast<s8v*>(fo + (size_t)vox * 32 + kc * 8) = pk;
    }

    // skip 1x1 conv via MFMA (weights first -> D rows = co, cols = vox)
    const s8v* __restrict__ wv = reinterpret_cast<const s8v*>(wsB);
    const s8v a0 = wv[m * 4 + kc];          // A rows co 0..15
    const s8v a1 = wv[(m + 16) * 4 + kc];   // A rows co 16..31
    f4v acc[2][8] = {};
#pragma unroll
    for (int nt = 0; nt < 8; ++nt) {
        acc[0][nt] = __builtin_amdgcn_mfma_f32_16x16x32_bf16(a0, bfrag[nt], acc[0][nt], 0, 0, 0);
        acc[1][nt] = __builtin_amdgcn_mfma_f32_16x16x32_bf16(a1, bfrag[nt], acc[1][nt], 0, 0, 0);
    }

    // D: col = m = vox offset, row = kc*4+j (+16*mt) = co. Store [vox][co].
    ushort* __restrict__ sko = skipB + (size_t)img * NVOX * 32;
    float s0 = 0.f, q0 = 0.f, s1 = 0.f, q1 = 0.f;
#pragma unroll
    for (int mt = 0; mt < 2; ++mt) {
#pragma unroll
        for (int nt = 0; nt < 8; ++nt) {
            const f4v a = acc[mt][nt];
            ushort4 pk;
            float xs[4];
#pragma unroll
            for (int j = 0; j < 4; ++j) {
                const int co = mt * 16 + kc * 4 + j;
                xs[j] = a[j] + bsb[co];
            }
            pk.x = bfb(xs[0]); pk.y = bfb(xs[1]); pk.z = bfb(xs[2]); pk.w = bfb(xs[3]);
            *reinterpret_cast<ushort4*>(
                sko + (size_t)(vb + nt * 16 + m) * 32 + mt * 16 + kc * 4) = pk;
#pragma unroll
            for (int j = 0; j < 4; ++j) {
                if (mt == 0) { s0 += xs[j]; q0 += xs[j] * xs[j]; }
                else         { s1 += xs[j]; q1 += xs[j] * xs[j]; }
            }
        }
    }

    __shared__ float red[4][8];
    float v4[4] = {s0, q0, s1, q1};
#pragma unroll
    for (int k = 0; k < 4; ++k) {
        float x = v4[k];
        x += __shfl_xor(x, 1, 64);
        x += __shfl_xor(x, 2, 64);
        x += __shfl_xor(x, 4, 64);
        x += __shfl_xor(x, 8, 64);
        x += __shfl_xor(x, 16, 64);
        v4[k] = x;
    }
    if (lane == 0)  { red[wid][0] = v4[0]; red[wid][1] = v4[1]; red[wid][4] = v4[2]; red[wid][5] = v4[3]; }
    if (lane == 32) { red[wid][2] = v4[0]; red[wid][3] = v4[1]; red[wid][6] = v4[2]; red[wid][7] = v4[3]; }
    __syncthreads();
    if (t < 8) {
        atomicAdd(&stats[img * 24 + 16 + t],
                  red[0][t] + red[1][t] + red[2][t] + red[3][t]);
    }
}

// ---------------------------------------------------------------------------
// 3x3x3 conv 32->32 via bf16 MFMA implicit GEMM, zero pad, +bias, +GN stats.
// Round-11 structure (measured 49us) with global_load_lds staging:
// LDS written linearly in wave order; per-lane GLOBAL source swizzle maps
// slot -> (ciq = slot/1226, r = slot%1226) of the plane layout; OOB lanes
// read a 64B zero page. Read side byte-identical to round 11.
// grid: (512 = 16bh x 16bw x 2bd, 2 images); 256 thr (4 waves).
// ---------------------------------------------------------------------------
__global__ __launch_bounds__(256) void conv3_mfma_kernel(
    const ushort* __restrict__ inB,
    const ushort* __restrict__ wB, const float* __restrict__ bias,
    const ushort* __restrict__ zeroPg,
    ushort* __restrict__ outB, float* __restrict__ stats, int layer)
{
    __shared__ __align__(16) ushort tile[4 * 1226 * 8];   // 78464 B
    __shared__ float red[4][8];

    const int img = blockIdx.y;
    const ushort* __restrict__ src = inB + (size_t)img * NVOX * 32;
    const int bx = blockIdx.x;
    const int bd = bx & 1, bw = (bx >> 1) & 15, bh = bx >> 5;
    const int t = threadIdx.x;
    const int lane = t & 63, wid = t >> 6;

    // ---- stage halo tile via global_load_lds (19 full wave iterations) ----
    const int gd0 = bd * 32 - 1, gh0 = bh * 4 - 1, gw0 = bw * 4 - 1;
#pragma unroll
    for (int it = 0; it < 19; ++it) {
        const int slot = it * 256 + t;          // 0..4863
        const int ciq = slot / 1226;
        const int r   = slot - ciq * 1226;
        const int hw = r / 34, dd = r - hw * 34;
        const int hh = hw / 6, ww = hw - hh * 6;
        const int gh = gh0 + hh, gw = gw0 + ww, gd = gd0 + dd;
        const bool ok = (r < 1224) && ((unsigned)gh < 64u) && ((unsigned)gw < 64u)
                        && ((unsigned)gd < 64u);
        const ushort* gp = ok
            ? (src + (size_t)(((gh << 12) + (gw << 6) + gd) << 5) + (ciq << 3))
            : zeroPg;
        __builtin_amdgcn_global_load_lds(
            (const __attribute__((address_space(1))) void*)gp,
            (__attribute__((address_space(3))) void*)(tile + (size_t)(it * 256 + wid * 64) * 8),
            16, 0, 0);
    }
    // tail: slots 4864..4903 via reg path
    if (t < 40) {
        const int slot = 4864 + t;
        const int ciq = slot / 1226;
        const int r   = slot - ciq * 1226;
        const int hw = r / 34, dd = r - hw * 34;
        const int hh = hw / 6, ww = hw - hh * 6;
        const int gh = gh0 + hh, gw = gw0 + ww, gd = gd0 + dd;
        s8v val = {0, 0, 0, 0, 0, 0, 0, 0};
        if ((r < 1224) && ((unsigned)gh < 64u) && ((unsigned)gw < 64u) && ((unsigned)gd < 64u))
            val = *reinterpret_cast<const s8v*>(
                src + (size_t)(((gh << 12) + (gw << 6) + gd) << 5) + (ciq << 3));
        reinterpret_cast<s8v*>(tile)[slot] = val;
    }
    __syncthreads();

    // ---- MFMA main loop (byte-identical to round 11) ----
    const int m = lane & 15, kc = lane >> 4;

    int pre8[4][2];   // A-frag row base per (w'=i, d-subtile dt)
#pragma unroll
    for (int i = 0; i < 4; ++i)
#pragma unroll
    for (int dt = 0; dt < 2; ++dt)
        pre8[i][dt] = kc * 1226 + (wid * 6 + i) * 34 + dt * 16 + m;

    const int wlane = m * 4 + kc;   // B-frag s8v offset within a tap
    const s8v* __restrict__ tv = reinterpret_cast<const s8v*>(tile);
    const s8v* __restrict__ wv = reinterpret_cast<const s8v*>(wB);

    f4v acc[4][2][2] = {};
#pragma unroll
    for (int tap = 0; tap < 27; ++tap) {
        const int dh = tap / 9, dw = (tap / 3) % 3, dd = tap % 3;
        const int toff = (dh * 6 + dw) * 34 + dd;
        const s8v bf0 = wv[tap * 128 + wlane];        // co = m
        const s8v bf1 = wv[tap * 128 + 64 + wlane];   // co = m+16
#pragma unroll
        for (int i = 0; i < 4; ++i)
#pragma unroll
        for (int dt = 0; dt < 2; ++dt) {
            const s8v a = tv[pre8[i][dt] + toff];
            acc[i][dt][0] = __builtin_amdgcn_mfma_f32_16x16x32_bf16(a, bf0, acc[i][dt][0], 0, 0, 0);
            acc[i][dt][1] = __builtin_amdgcn_mfma_f32_16x16x32_bf16(a, bf1, acc[i][dt][1], 0, 0, 0);
        }
    }

    // ---- epilogue: +bias, bf16 ushort4 store along d, GN stats (fp32) ----
    ushort* __restrict__ outi = outB + (size_t)img * NB32;
    const float b0 = bias[m], b1 = bias[m + 16];
    ushort* __restrict__ op0 = outi + (size_t)m * NVOX;           // co = m
    ushort* __restrict__ op1 = outi + (size_t)(m + 16) * NVOX;    // co = m+16
    const int vbase = ((bh * 4 + wid) << 12) + ((bw * 4) << 6) + bd * 32 + kc * 4;
    float gsum[2] = {0.f, 0.f}, gsq[2] = {0.f, 0.f};
#pragma unroll
    for (int i = 0; i < 4; ++i) {
#pragma unroll
        for (int dt = 0; dt < 2; ++dt) {
            const int v = vbase + (i << 6) + dt * 16;
#pragma unroll
            for (int nt = 0; nt < 2; ++nt) {
                const f4v a = acc[i][dt][nt];
                const float bb = nt ? b1 : b0;
                const float x0 = a[0] + bb, x1 = a[1] + bb, x2 = a[2] + bb, x3 = a[3] + bb;
                ushort4 pk;
                pk.x = bfb(x0); pk.y = bfb(x1); pk.z = bfb(x2); pk.w = bfb(x3);
                *reinterpret_cast<ushort4*>((nt ? op1 : op0) + v) = pk;
                gsum[nt] += x0 + x1 + x2 + x3;
                gsq[nt]  += x0 * x0 + x1 * x1 + x2 * x2 + x3 * x3;
            }
        }
    }

#pragma unroll
    for (int nt = 0; nt < 2; ++nt) {
        float s = gsum[nt], q = gsq[nt];
        s += __shfl_xor(s, 16, 64); q += __shfl_xor(q, 16, 64);
        s += __shfl_xor(s, 32, 64); q += __shfl_xor(q, 32, 64);
        s += __shfl_xor(s, 1, 64);  q += __shfl_xor(q, 1, 64);
        s += __shfl_xor(s, 2, 64);  q += __shfl_xor(q, 2, 64);
        s += __shfl_xor(s, 4, 64);  q += __shfl_xor(q, 4, 64);
        if (lane == 0) { const int g = nt * 2;     red[wid][g * 2] = s; red[wid][g * 2 + 1] = q; }
        if (lane == 8) { const int g = nt * 2 + 1; red[wid][g * 2] = s; red[wid][g * 2 + 1] = q; }
    }
    __syncthreads();
    if (t < 8) {
        atomicAdd(&stats[img * 24 + layer * 8 + t],
                  red[0][t] + red[1][t] + red[2][t] + red[3][t]);
    }
}

// ---------------------------------------------------------------------------
// GN1 apply + lrelu: cA bf16 [c][vox] -> bf16 [vox][ci]
// vectorized: each thread does 4 consecutive vox (ushort4 plane loads)
// grid: (256, 2 images)
// ---------------------------------------------------------------------------
__global__ __launch_bounds__(256) void gn_transpose_kernel(
    const ushort* __restrict__ cA, const float* __restrict__ stats,
    const float* __restrict__ gamma, const float* __restrict__ beta,
    ushort* __restrict__ outB)
{
    const int img = blockIdx.y;
    const ushort* __restrict__ in = cA + (size_t)img * NB32;
    ushort* __restrict__ op = outB + (size_t)img * NVOX * 32;
    const int v4 = (blockIdx.x * 256 + threadIdx.x) * 4;
    const float Minv = 1.f / (8.f * (float)NVOX);
    float mu[4], rs[4];
#pragma unroll
    for (int g = 0; g < 4; ++g) {
        const float s = stats[img * 24 + 2 * g], q = stats[img * 24 + 2 * g + 1];
        mu[g] = s * Minv;
        rs[g] = rsqrtf(q * Minv - mu[g] * mu[g] + 1e-5f);
    }
    s8v outv[4][4];   // [vox k][ci quad]
#pragma unroll
    for (int c = 0; c < 32; ++c) {
        const int g = c >> 3;
        const float sc = rs[g] * gamma[c];
        const float sh = beta[c] - mu[g] * sc;
        const ushort4 ld = *reinterpret_cast<const ushort4*>(in + (size_t)c * NVOX + v4);
        float y0 = bf2f(ld.x) * sc + sh; y0 = fmaxf(y0, 0.2f * y0);
        float y1 = bf2f(ld.y) * sc + sh; y1 = fmaxf(y1, 0.2f * y1);
        float y2 = bf2f(ld.z) * sc + sh; y2 = fmaxf(y2, 0.2f * y2);
        float y3 = bf2f(ld.w) * sc + sh; y3 = fmaxf(y3, 0.2f * y3);
        outv[0][c >> 3][c & 7] = (short)bfb(y0);
        outv[1][c >> 3][c & 7] = (short)bfb(y1);
        outv[2][c >> 3][c & 7] = (short)bfb(y2);
        outv[3][c >> 3][c & 7] = (short)bfb(y3);
    }
#pragma unroll
    for (int k = 0; k < 4; ++k)
#pragma unroll
    for (int cq = 0; cq < 4; ++cq)
        *reinterpret_cast<s8v*>(op + (size_t)(v4 + k) * 32 + cq * 8) = outv[k][cq];
}

// ---------------------------------------------------------------------------
// combine: GN2(cB [co][vox] strided) + GN3(skipB [vox][co] vectorized),
// residual add, lrelu, project to 16 emb ch -> embB bf16 [img][vox][16]
// ---------------------------------------------------------------------------
__global__ __launch_bounds__(256) void combine_kernel(
    const ushort* __restrict__ Bb, const ushort* __restrict__ Sk,
    const float* __restrict__ stats,
    const float* __restrict__ g2, const float* __restrict__ be2,
    const float* __restrict__ gs, const float* __restrict__ bes,
    const float* __restrict__ wp, const float* __restrict__ bp,
    ushort* __restrict__ embB)
{
    const int img = blockIdx.y;
    const int v   = blockIdx.x * 256 + threadIdx.x;
    const float Minv = 1.f / (8.f * (float)NVOX);
    float mu1[4], rs1[4], mu2[4], rs2[4];
#pragma unroll
    for (int g = 0; g < 4; ++g) {
        float s = stats[img * 24 + 8 + 2 * g], q = stats[img * 24 + 8 + 2 * g + 1];
        mu1[g] = s * Minv; rs1[g] = rsqrtf(q * Minv - mu1[g] * mu1[g] + 1e-5f);
        s = stats[img * 24 + 16 + 2 * g]; q = stats[img * 24 + 16 + 2 * g + 1];
        mu2[g] = s * Minv; rs2[g] = rsqrtf(q * Minv - mu2[g] * mu2[g] + 1e-5f);
    }
    const ushort* __restrict__ bb = Bb + (size_t)img * NB32;
    const ushort* __restrict__ sk = Sk + ((size_t)img * NVOX + v) * 32;
    float o[32];
#pragma unroll
    for (int cq = 0; cq < 4; ++cq) {
        const s8v sv8 = *reinterpret_cast<const s8v*>(sk + cq * 8);
#pragma unroll
        for (int j = 0; j < 8; ++j) {
            const int c = cq * 8 + j;
            const int g = c >> 3;
            const float hv = (bf2f(bb[c * NVOX + v]) - mu1[g]) * rs1[g] * g2[c] + be2[c];
            const float sv = (bf2f((ushort)sv8[j]) - mu2[g]) * rs2[g] * gs[c] + bes[c];
            const float tv = hv + sv;
            o[c] = tv >= 0.f ? tv : 0.2f * tv;
        }
    }
    ushort* __restrict__ eo = embB + ((size_t)img * NVOX + v) * 16;
#pragma unroll
    for (int eq = 0; eq < 2; ++eq) {
        s8v pk;
#pragma unroll
        for (int j = 0; j < 8; ++j) {
            const int e = eq * 8 + j;
            float s = bp[e];
#pragma unroll
            for (int c = 0; c < 32; ++c) s += wp[e * 32 + c] * o[c];
            pk[j] = (short)bfb(s);
        }
        *reinterpret_cast<s8v*>(eo + eq * 8) = pk;
    }
}

// ---------------------------------------------------------------------------
// attention: Q = embB[fixed][v][:], K gathered from embB[moving] (edge clamp),
// softmax over 27 neighbors, displacement = sum attn * offset (fp32 out)
// ---------------------------------------------------------------------------
__global__ __launch_bounds__(256) void attn_kernel(
    const ushort* __restrict__ embB, float* __restrict__ out)
{
    const int v = blockIdx.x * 256 + threadIdx.x;
    const int h = v >> 12, w = (v >> 6) & 63, d = v & 63;
    const ushort* __restrict__ Qp = embB + (size_t)v * 16;
    const ushort* __restrict__ Kp = embB + (size_t)NVOX * 16;
    float q[16];
    {
        const s8v q0 = *reinterpret_cast<const s8v*>(Qp);
        const s8v q1 = *reinterpret_cast<const s8v*>(Qp + 8);
#pragma unroll
        for (int j = 0; j < 8; ++j) { q[j] = bf2f((ushort)q0[j]); q[8 + j] = bf2f((ushort)q1[j]); }
    }
    float sc[27];
    float m = -1e30f;
#pragma unroll
    for (int ih = 0; ih < 3; ++ih)
#pragma unroll
    for (int iw = 0; iw < 3; ++iw)
#pragma unroll
    for (int id = 0; id < 3; ++id) {
        int hh = h + ih - 1; hh = hh < 0 ? 0 : (hh > 63 ? 63 : hh);
        int ww = w + iw - 1; ww = ww < 0 ? 0 : (ww > 63 ? 63 : ww);
        int dd = d + id - 1; dd = dd < 0 ? 0 : (dd > 63 ? 63 : dd);
        const ushort* __restrict__ kp = Kp + (size_t)((hh << 12) + (ww << 6) + dd) * 16;
        const s8v k0 = *reinterpret_cast<const s8v*>(kp);
        const s8v k1 = *reinterpret_cast<const s8v*>(kp + 8);
        float s = 0.f;
#pragma unroll
        for (int j = 0; j < 8; ++j)
            s += q[j] * bf2f((ushort)k0[j]) + q[8 + j] * bf2f((ushort)k1[j]);
        s *= 0.25f;   // / sqrt(16)
        sc[(ih * 3 + iw) * 3 + id] = s;
        m = fmaxf(m, s);
    }
    float den = 0.f;
#pragma unroll
    for (int p = 0; p < 27; ++p) { sc[p] = __expf(sc[p] - m); den += sc[p]; }
    const float inv = 1.f / den;
    float r0 = 0.f, r1 = 0.f, r2 = 0.f;
#pragma unroll
    for (int ih = 0; ih < 3; ++ih)
#pragma unroll
    for (int iw = 0; iw < 3; ++iw)
#pragma unroll
    for (int id = 0; id < 3; ++id) {
        const float a = sc[(ih * 3 + iw) * 3 + id] * inv;
        r0 += a * (float)(ih - 1);
        r1 += a * (float)(iw - 1);
        r2 += a * (float)(id - 1);
    }
    out[v]            = r0;
    out[NVOX + v]     = r1;
    out[2 * NVOX + v] = r2;
}

// ---------------------------------------------------------------------------
extern "C" void kernel_launch(void* const* d_in, const int* in_sizes, int n_in,
                              void* d_out, int out_size, void* d_ws, size_t ws_size,
                              hipStream_t stream)
{
    (void)in_sizes; (void)n_in; (void)out_size; (void)ws_size;
    const float* feat_moving = (const float*)d_in[0];
    const float* feat_fixed  = (const float*)d_in[1];
    const float* w1  = (const float*)d_in[2];
    const float* b1  = (const float*)d_in[3];
    const float* g1  = (const float*)d_in[4];
    const float* be1 = (const float*)d_in[5];
    const float* w2  = (const float*)d_in[6];
    const float* b2  = (const float*)d_in[7];
    const float* g2  = (const float*)d_in[8];
    const float* be2 = (const float*)d_in[9];
    const float* wsw = (const float*)d_in[10];
    const float* bs  = (const float*)d_in[11];
    const float* gs  = (const float*)d_in[12];
    const float* bes = (const float*)d_in[13];
    const float* wp  = (const float*)d_in[14];
    const float* bp  = (const float*)d_in[15];

    // workspace by lifetime (MiB offsets), max ~160.1 MiB:
    //   featB [0,32)   bf16 [vox][ci]   live tobf_skip..conv1 ; embB aliases
    //   cA    [32,64)  bf16 [co][vox]   live conv1..gn_t
    //   AB    [64,96)  bf16 [vox][ci]   live gn_t..conv2
    //   cB    [96,128) bf16 [co][vox]   live conv2..combine
    //   skipB [128,160)bf16 [vox][co]   live tobf_skip..combine
    //   embB = featB region, bf16 [img][vox][16], live combine..attn
    //   stats[0..47] GN stats; stats[48..63] = 64B zero page for conv staging
    char* base = (char*)d_ws;
    ushort* featB = (ushort*)base;
    ushort* cA    = (ushort*)(base + (32ull << 20));
    ushort* AB    = (ushort*)(base + (64ull << 20));
    ushort* cB    = (ushort*)(base + (96ull << 20));
    ushort* skipB = (ushort*)(base + (128ull << 20));
    ushort* embB  = (ushort*)base;
    float*  stats = (float*)(base + (160ull << 20));
    const ushort* zeroPg = (const ushort*)(stats + 48);
    ushort* wB1   = (ushort*)(stats + 64);
    ushort* wB2   = wB1 + 27648;
    ushort* wsB   = wB2 + 27648;

    prep_kernel<<<108, 256, 0, stream>>>(w1, w2, wsw, wB1, wB2, wsB, stats);
    tobf_skip_kernel<<<dim3(512, 2), 256, 0, stream>>>(feat_fixed, feat_moving, wsB, bs,
                                                       featB, skipB, stats);
    conv3_mfma_kernel<<<dim3(512, 2), 256, 0, stream>>>(featB, wB1, b1, zeroPg, cA, stats, 0);
    gn_transpose_kernel<<<dim3(256, 2), 256, 0, stream>>>(cA, stats, g1, be1, AB);
    conv3_mfma_kernel<<<dim3(512, 2), 256, 0, stream>>>(AB, wB2, b2, zeroPg, cB, stats, 1);
    combine_kernel<<<dim3(1024, 2), 256, 0, stream>>>(cB, skipB, stats, g2, be2, gs, bes,
                                                      wp, bp, embB);
    attn_kernel<<<1024, 256, 0, stream>>>(embB, (float*)d_out);
}

// Round 16
// 168.991 us; speedup vs baseline: 1.2582x; 1.0116x over previous
//
#include <hip/hip_runtime.h>
#include <hip/hip_bf16.h>

#define NVOX (64*64*64)      // 262144 = 2^18
#define NB32 (32*NVOX)       // 2^23 elements per image of 32-ch volume

typedef short s8v __attribute__((ext_vector_type(8)));   // 8 bf16 = 4 VGPR (MFMA A/B frag)
typedef float f4v __attribute__((ext_vector_type(4)));   // MFMA C/D frag

__device__ inline ushort bfb(float f) {
    __hip_bfloat16 h = __float2bfloat16(f);
    return *reinterpret_cast<ushort*>(&h);
}
__device__ inline float bf2f(ushort u) {
    unsigned x = (unsigned)u << 16;
    return __builtin_bit_cast(float, x);
}

// ---------------------------------------------------------------------------
// prep: conv weights [co][ci][tap] -> bf16 [tap][co][ci]; skip W -> bf16 [co][ci];
// zero stats[0..63] (stats+48 doubles as the 64B zero page for conv staging)
// ---------------------------------------------------------------------------
__global__ __launch_bounds__(256) void prep_kernel(
    const float* __restrict__ w1, const float* __restrict__ w2,
    const float* __restrict__ wsw,
    ushort* __restrict__ wB1, ushort* __restrict__ wB2,
    ushort* __restrict__ wsB, float* __restrict__ stats)
{
    if (blockIdx.x == 0 && threadIdx.x < 64) stats[threadIdx.x] = 0.f;
    int i = blockIdx.x * 256 + threadIdx.x;
    if (i < 1024) wsB[i] = bfb(wsw[i]);              // [co][ci]
    if (i < 32 * 32 * 27) {
        int co  = i / 864;            // 864 = 32*27
        int rem = i - co * 864;
        int ci  = rem / 27;
        int tap = rem - ci * 27;
        wB1[(tap * 32 + co) * 32 + ci] = bfb(w1[i]);
        wB2[(tap * 32 + co) * 32 + ci] = bfb(w2[i]);
    }
}

// ---------------------------------------------------------------------------
// fused: feat fp32 [c][vox] -> featB bf16 [vox][ci]
//        + skip 1x1 conv via MFMA -> skipB bf16 [vox][co] + GN3 stats.
// Wave covers 128 vox (nt=0..7) for 2x load ILP. grid: (512, 2 images)
// ---------------------------------------------------------------------------
__global__ __launch_bounds__(256) void tobf_skip_kernel(
    const float* __restrict__ in0, const float* __restrict__ in1,
    const ushort* __restrict__ wsB, const float* __restrict__ bsb,
    ushort* __restrict__ featB, ushort* __restrict__ skipB,
    float* __restrict__ stats)
{
    const int img = blockIdx.y;
    const float* __restrict__ in = img ? in1 : in0;
    const int t = threadIdx.x;
    const int lane = t & 63, wid = t >> 6;
    const int m = lane & 15, kc = lane >> 4;
    const int vb = blockIdx.x * 512 + wid * 128;   // wave's vox base

    ushort* __restrict__ fo = featB + (size_t)img * NVOX * 32;

    // load + convert + store featB; keep as B-frags (col=vox, k=ci)
    s8v bfrag[8];
#pragma unroll
    for (int nt = 0; nt < 8; ++nt) {
        const int vox = vb + nt * 16 + m;
        s8v pk;
#pragma unroll
        for (int j = 0; j < 8; ++j)
            pk[j] = (short)bfb(in[(kc * 8 + j) * NVOX + vox]);
        bfrag[nt] = pk;
        *reinterpret_cast<s8v*>(fo + (size_t)vox * 32 + kc * 8) = pk;
    }

    // skip 1x1 conv via MFMA (weights first -> D rows = co, cols = vox)
    const s8v* __restrict__ wv = reinterpret_cast<const s8v*>(wsB);
    const s8v a0 = wv[m * 4 + kc];          // A rows co 0..15
    const s8v a1 = wv[(m + 16) * 4 + kc];   // A rows co 16..31
    f4v acc[2][8] = {};
#pragma unroll
    for (int nt = 0; nt < 8; ++nt) {
        acc[0][nt] = __builtin_amdgcn_mfma_f32_16x16x32_bf16(a0, bfrag[nt], acc[0][nt], 0, 0, 0);
        acc[1][nt] = __builtin_amdgcn_mfma_f32_16x16x32_bf16(a1, bfrag[nt], acc[1][nt], 0, 0, 0);
    }

    // D: col = m = vox offset, row = kc*4+j (+16*mt) = co. Store [vox][co].
    ushort* __restrict__ sko = skipB + (size_t)img * NVOX * 32;
    float s0 = 0.f, q0 = 0.f, s1 = 0.f, q1 = 0.f;
#pragma unroll
    for (int mt = 0; mt < 2; ++mt) {
#pragma unroll
        for (int nt = 0; nt < 8; ++nt) {
            const f4v a = acc[mt][nt];
            ushort4 pk;
            float xs[4];
#pragma unroll
            for (int j = 0; j < 4; ++j) {
                const int co = mt * 16 + kc * 4 + j;
                xs[j] = a[j] + bsb[co];
            }
            pk.x = bfb(xs[0]); pk.y = bfb(xs[1]); pk.z = bfb(xs[2]); pk.w = bfb(xs[3]);
            *reinterpret_cast<ushort4*>(
                sko + (size_t)(vb + nt * 16 + m) * 32 + mt * 16 + kc * 4) = pk;
#pragma unroll
            for (int j = 0; j < 4; ++j) {
                if (mt == 0) { s0 += xs[j]; q0 += xs[j] * xs[j]; }
                else         { s1 += xs[j]; q1 += xs[j] * xs[j]; }
            }
        }
    }

    __shared__ float red[4][8];
    float v4[4] = {s0, q0, s1, q1};
#pragma unroll
    for (int k = 0; k < 4; ++k) {
        float x = v4[k];
        x += __shfl_xor(x, 1, 64);
        x += __shfl_xor(x, 2, 64);
        x += __shfl_xor(x, 4, 64);
        x += __shfl_xor(x, 8, 64);
        x += __shfl_xor(x, 16, 64);
        v4[k] = x;
    }
    if (lane == 0)  { red[wid][0] = v4[0]; red[wid][1] = v4[1]; red[wid][4] = v4[2]; red[wid][5] = v4[3]; }
    if (lane == 32) { red[wid][2] = v4[0]; red[wid][3] = v4[1]; red[wid][6] = v4[2]; red[wid][7] = v4[3]; }
    __syncthreads();
    if (t < 8) {
        atomicAdd(&stats[img * 24 + 16 + t],
                  red[0][t] + red[1][t] + red[2][t] + red[3][t]);
    }
}

// ---------------------------------------------------------------------------
// 3x3x3 conv 32->32 via bf16 MFMA implicit GEMM, zero pad, +bias, +GN stats.
// Round-15 staging (global_load_lds + zero page). NEW: register-blocked
// A-fragments — loop dh,dd loads 12 frags (6 hw-rows x 2 dt) once, reused
// across dw (fr[i+dw]); ds_reads 216 -> 108 per wave, identical math.
// grid: (512 = 16bh x 16bw x 2bd, 2 images); 256 thr (4 waves).
// ---------------------------------------------------------------------------
__global__ __launch_bounds__(256) void conv3_mfma_kernel(
    const ushort* __restrict__ inB,
    const ushort* __restrict__ wB, const float* __restrict__ bias,
    const ushort* __restrict__ zeroPg,
    ushort* __restrict__ outB, float* __restrict__ stats, int layer)
{
    __shared__ __align__(16) ushort tile[4 * 1226 * 8];   // 78464 B
    __shared__ float red[4][8];

    const int img = blockIdx.y;
    const ushort* __restrict__ src = inB + (size_t)img * NVOX * 32;
    const int bx = blockIdx.x;
    const int bd = bx & 1, bw = (bx >> 1) & 15, bh = bx >> 5;
    const int t = threadIdx.x;
    const int lane = t & 63, wid = t >> 6;

    // ---- stage halo tile via global_load_lds (19 full wave iterations) ----
    const int gd0 = bd * 32 - 1, gh0 = bh * 4 - 1, gw0 = bw * 4 - 1;
#pragma unroll
    for (int it = 0; it < 19; ++it) {
        const int slot = it * 256 + t;          // 0..4863
        const int ciq = slot / 1226;
        const int r   = slot - ciq * 1226;
        const int hw = r / 34, dd = r - hw * 34;
        const int hh = hw / 6, ww = hw - hh * 6;
        const int gh = gh0 + hh, gw = gw0 + ww, gd = gd0 + dd;
        const bool ok = (r < 1224) && ((unsigned)gh < 64u) && ((unsigned)gw < 64u)
                        && ((unsigned)gd < 64u);
        const ushort* gp = ok
            ? (src + (size_t)(((gh << 12) + (gw << 6) + gd) << 5) + (ciq << 3))
            : zeroPg;
        __builtin_amdgcn_global_load_lds(
            (const __attribute__((address_space(1))) void*)gp,
            (__attribute__((address_space(3))) void*)(tile + (size_t)(it * 256 + wid * 64) * 8),
            16, 0, 0);
    }
    // tail: slots 4864..4903 via reg path
    if (t < 40) {
        const int slot = 4864 + t;
        const int ciq = slot / 1226;
        const int r   = slot - ciq * 1226;
        const int hw = r / 34, dd = r - hw * 34;
        const int hh = hw / 6, ww = hw - hh * 6;
        const int gh = gh0 + hh, gw = gw0 + ww, gd = gd0 + dd;
        s8v val = {0, 0, 0, 0, 0, 0, 0, 0};
        if ((r < 1224) && ((unsigned)gh < 64u) && ((unsigned)gw < 64u) && ((unsigned)gd < 64u))
            val = *reinterpret_cast<const s8v*>(
                src + (size_t)(((gh << 12) + (gw << 6) + gd) << 5) + (ciq << 3));
        reinterpret_cast<s8v*>(tile)[slot] = val;
    }
    __syncthreads();

    // ---- MFMA main loop: register-blocked A-frags, mfma(a, w) order ----
    const int m = lane & 15, kc = lane >> 4;
    const int wlane = m * 4 + kc;   // B-frag s8v offset within a tap
    const s8v* __restrict__ tv = reinterpret_cast<const s8v*>(tile);
    const s8v* __restrict__ wv = reinterpret_cast<const s8v*>(wB);

    f4v acc[4][2][2] = {};
#pragma unroll
    for (int dh = 0; dh < 3; ++dh) {
#pragma unroll
        for (int dd = 0; dd < 3; ++dd) {
            // load 12 fragments: 6 hw-rows x 2 d-subtiles, each reused up to 3x
            s8v fr[6][2];
            const int rbase = kc * 1226 + ((wid + dh) * 6) * 34 + m + dd;
#pragma unroll
            for (int j = 0; j < 6; ++j)
#pragma unroll
            for (int dt = 0; dt < 2; ++dt)
                fr[j][dt] = tv[rbase + j * 34 + dt * 16];
#pragma unroll
            for (int dw = 0; dw < 3; ++dw) {
                const int tap = dh * 9 + dw * 3 + dd;
                const s8v bf0 = wv[tap * 128 + wlane];        // co = m
                const s8v bf1 = wv[tap * 128 + 64 + wlane];   // co = m+16
#pragma unroll
                for (int i = 0; i < 4; ++i)
#pragma unroll
                for (int dt = 0; dt < 2; ++dt) {
                    acc[i][dt][0] = __builtin_amdgcn_mfma_f32_16x16x32_bf16(fr[i + dw][dt], bf0, acc[i][dt][0], 0, 0, 0);
                    acc[i][dt][1] = __builtin_amdgcn_mfma_f32_16x16x32_bf16(fr[i + dw][dt], bf1, acc[i][dt][1], 0, 0, 0);
                }
            }
        }
    }

    // ---- epilogue: +bias, bf16 ushort4 store along d, GN stats (fp32) ----
    ushort* __restrict__ outi = outB + (size_t)img * NB32;
    const float b0 = bias[m], b1 = bias[m + 16];
    ushort* __restrict__ op0 = outi + (size_t)m * NVOX;           // co = m
    ushort* __restrict__ op1 = outi + (size_t)(m + 16) * NVOX;    // co = m+16
    const int vbase = ((bh * 4 + wid) << 12) + ((bw * 4) << 6) + bd * 32 + kc * 4;
    float gsum[2] = {0.f, 0.f}, gsq[2] = {0.f, 0.f};
#pragma unroll
    for (int i = 0; i < 4; ++i) {
#pragma unroll
        for (int dt = 0; dt < 2; ++dt) {
            const int v = vbase + (i << 6) + dt * 16;
#pragma unroll
            for (int nt = 0; nt < 2; ++nt) {
                const f4v a = acc[i][dt][nt];
                const float bb = nt ? b1 : b0;
                const float x0 = a[0] + bb, x1 = a[1] + bb, x2 = a[2] + bb, x3 = a[3] + bb;
                ushort4 pk;
                pk.x = bfb(x0); pk.y = bfb(x1); pk.z = bfb(x2); pk.w = bfb(x3);
                *reinterpret_cast<ushort4*>((nt ? op1 : op0) + v) = pk;
                gsum[nt] += x0 + x1 + x2 + x3;
                gsq[nt]  += x0 * x0 + x1 * x1 + x2 * x2 + x3 * x3;
            }
        }
    }

#pragma unroll
    for (int nt = 0; nt < 2; ++nt) {
        float s = gsum[nt], q = gsq[nt];
        s += __shfl_xor(s, 16, 64); q += __shfl_xor(q, 16, 64);
        s += __shfl_xor(s, 32, 64); q += __shfl_xor(q, 32, 64);
        s += __shfl_xor(s, 1, 64);  q += __shfl_xor(q, 1, 64);
        s += __shfl_xor(s, 2, 64);  q += __shfl_xor(q, 2, 64);
        s += __shfl_xor(s, 4, 64);  q += __shfl_xor(q, 4, 64);
        if (lane == 0) { const int g = nt * 2;     red[wid][g * 2] = s; red[wid][g * 2 + 1] = q; }
        if (lane == 8) { const int g = nt * 2 + 1; red[wid][g * 2] = s; red[wid][g * 2 + 1] = q; }
    }
    __syncthreads();
    if (t < 8) {
        atomicAdd(&stats[img * 24 + layer * 8 + t],
                  red[0][t] + red[1][t] + red[2][t] + red[3][t]);
    }
}

// ---------------------------------------------------------------------------
// GN1 apply + lrelu: cA bf16 [c][vox] -> bf16 [vox][ci]
// vectorized: each thread does 4 consecutive vox (ushort4 plane loads)
// grid: (256, 2 images)
// ---------------------------------------------------------------------------
__global__ __launch_bounds__(256) void gn_transpose_kernel(
    const ushort* __restrict__ cA, const float* __restrict__ stats,
    const float* __restrict__ gamma, const float* __restrict__ beta,
    ushort* __restrict__ outB)
{
    const int img = blockIdx.y;
    const ushort* __restrict__ in = cA + (size_t)img * NB32;
    ushort* __restrict__ op = outB + (size_t)img * NVOX * 32;
    const int v4 = (blockIdx.x * 256 + threadIdx.x) * 4;
    const float Minv = 1.f / (8.f * (float)NVOX);
    float mu[4], rs[4];
#pragma unroll
    for (int g = 0; g < 4; ++g) {
        const float s = stats[img * 24 + 2 * g], q = stats[img * 24 + 2 * g + 1];
        mu[g] = s * Minv;
        rs[g] = rsqrtf(q * Minv - mu[g] * mu[g] + 1e-5f);
    }
    s8v outv[4][4];   // [vox k][ci quad]
#pragma unroll
    for (int c = 0; c < 32; ++c) {
        const int g = c >> 3;
        const float sc = rs[g] * gamma[c];
        const float sh = beta[c] - mu[g] * sc;
        const ushort4 ld = *reinterpret_cast<const ushort4*>(in + (size_t)c * NVOX + v4);
        float y0 = bf2f(ld.x) * sc + sh; y0 = fmaxf(y0, 0.2f * y0);
        float y1 = bf2f(ld.y) * sc + sh; y1 = fmaxf(y1, 0.2f * y1);
        float y2 = bf2f(ld.z) * sc + sh; y2 = fmaxf(y2, 0.2f * y2);
        float y3 = bf2f(ld.w) * sc + sh; y3 = fmaxf(y3, 0.2f * y3);
        outv[0][c >> 3][c & 7] = (short)bfb(y0);
        outv[1][c >> 3][c & 7] = (short)bfb(y1);
        outv[2][c >> 3][c & 7] = (short)bfb(y2);
        outv[3][c >> 3][c & 7] = (short)bfb(y3);
    }
#pragma unroll
    for (int k = 0; k < 4; ++k)
#pragma unroll
    for (int cq = 0; cq < 4; ++cq)
        *reinterpret_cast<s8v*>(op + (size_t)(v4 + k) * 32 + cq * 8) = outv[k][cq];
}

// ---------------------------------------------------------------------------
// combine: GN2(cB [co][vox] strided) + GN3(skipB [vox][co] vectorized),
// residual add, lrelu, project to 16 emb ch -> embB bf16 [img][vox][16]
// ---------------------------------------------------------------------------
__global__ __launch_bounds__(256) void combine_kernel(
    const ushort* __restrict__ Bb, const ushort* __restrict__ Sk,
    const float* __restrict__ stats,
    const float* __restrict__ g2, const float* __restrict__ be2,
    const float* __restrict__ gs, const float* __restrict__ bes,
    const float* __restrict__ wp, const float* __restrict__ bp,
    ushort* __restrict__ embB)
{
    const int img = blockIdx.y;
    const int v   = blockIdx.x * 256 + threadIdx.x;
    const float Minv = 1.f / (8.f * (float)NVOX);
    float mu1[4], rs1[4], mu2[4], rs2[4];
#pragma unroll
    for (int g = 0; g < 4; ++g) {
        float s = stats[img * 24 + 8 + 2 * g], q = stats[img * 24 + 8 + 2 * g + 1];
        mu1[g] = s * Minv; rs1[g] = rsqrtf(q * Minv - mu1[g] * mu1[g] + 1e-5f);
        s = stats[img * 24 + 16 + 2 * g]; q = stats[img * 24 + 16 + 2 * g + 1];
        mu2[g] = s * Minv; rs2[g] = rsqrtf(q * Minv - mu2[g] * mu2[g] + 1e-5f);
    }
    const ushort* __restrict__ bb = Bb + (size_t)img * NB32;
    const ushort* __restrict__ sk = Sk + ((size_t)img * NVOX + v) * 32;
    float o[32];
#pragma unroll
    for (int cq = 0; cq < 4; ++cq) {
        const s8v sv8 = *reinterpret_cast<const s8v*>(sk + cq * 8);
#pragma unroll
        for (int j = 0; j < 8; ++j) {
            const int c = cq * 8 + j;
            const int g = c >> 3;
            const float hv = (bf2f(bb[c * NVOX + v]) - mu1[g]) * rs1[g] * g2[c] + be2[c];
            const float sv = (bf2f((ushort)sv8[j]) - mu2[g]) * rs2[g] * gs[c] + bes[c];
            const float tv = hv + sv;
            o[c] = tv >= 0.f ? tv : 0.2f * tv;
        }
    }
    ushort* __restrict__ eo = embB + ((size_t)img * NVOX + v) * 16;
#pragma unroll
    for (int eq = 0; eq < 2; ++eq) {
        s8v pk;
#pragma unroll
        for (int j = 0; j < 8; ++j) {
            const int e = eq * 8 + j;
            float s = bp[e];
#pragma unroll
            for (int c = 0; c < 32; ++c) s += wp[e * 32 + c] * o[c];
            pk[j] = (short)bfb(s);
        }
        *reinterpret_cast<s8v*>(eo + eq * 8) = pk;
    }
}

// ---------------------------------------------------------------------------
// attention: Q = embB[fixed][v][:], K gathered from embB[moving] (edge clamp),
// softmax over 27 neighbors, displacement = sum attn * offset (fp32 out)
// ---------------------------------------------------------------------------
__global__ __launch_bounds__(256) void attn_kernel(
    const ushort* __restrict__ embB, float* __restrict__ out)
{
    const int v = blockIdx.x * 256 + threadIdx.x;
    const int h = v >> 12, w = (v >> 6) & 63, d = v & 63;
    const ushort* __restrict__ Qp = embB + (size_t)v * 16;
    const ushort* __restrict__ Kp = embB + (size_t)NVOX * 16;
    float q[16];
    {
        const s8v q0 = *reinterpret_cast<const s8v*>(Qp);
        const s8v q1 = *reinterpret_cast<const s8v*>(Qp + 8);
#pragma unroll
        for (int j = 0; j < 8; ++j) { q[j] = bf2f((ushort)q0[j]); q[8 + j] = bf2f((ushort)q1[j]); }
    }
    float sc[27];
    float m = -1e30f;
#pragma unroll
    for (int ih = 0; ih < 3; ++ih)
#pragma unroll
    for (int iw = 0; iw < 3; ++iw)
#pragma unroll
    for (int id = 0; id < 3; ++id) {
        int hh = h + ih - 1; hh = hh < 0 ? 0 : (hh > 63 ? 63 : hh);
        int ww = w + iw - 1; ww = ww < 0 ? 0 : (ww > 63 ? 63 : ww);
        int dd = d + id - 1; dd = dd < 0 ? 0 : (dd > 63 ? 63 : dd);
        const ushort* __restrict__ kp = Kp + (size_t)((hh << 12) + (ww << 6) + dd) * 16;
        const s8v k0 = *reinterpret_cast<const s8v*>(kp);
        const s8v k1 = *reinterpret_cast<const s8v*>(kp + 8);
        float s = 0.f;
#pragma unroll
        for (int j = 0; j < 8; ++j)
            s += q[j] * bf2f((ushort)k0[j]) + q[8 + j] * bf2f((ushort)k1[j]);
        s *= 0.25f;   // / sqrt(16)
        sc[(ih * 3 + iw) * 3 + id] = s;
        m = fmaxf(m, s);
    }
    float den = 0.f;
#pragma unroll
    for (int p = 0; p < 27; ++p) { sc[p] = __expf(sc[p] - m); den += sc[p]; }
    const float inv = 1.f / den;
    float r0 = 0.f, r1 = 0.f, r2 = 0.f;
#pragma unroll
    for (int ih = 0; ih < 3; ++ih)
#pragma unroll
    for (int iw = 0; iw < 3; ++iw)
#pragma unroll
    for (int id = 0; id < 3; ++id) {
        const float a = sc[(ih * 3 + iw) * 3 + id] * inv;
        r0 += a * (float)(ih - 1);
        r1 += a * (float)(iw - 1);
        r2 += a * (float)(id - 1);
    }
    out[v]            = r0;
    out[NVOX + v]     = r1;
    out[2 * NVOX + v] = r2;
}

// ---------------------------------------------------------------------------
extern "C" void kernel_launch(void* const* d_in, const int* in_sizes, int n_in,
                              void* d_out, int out_size, void* d_ws, size_t ws_size,
                              hipStream_t stream)
{
    (void)in_sizes; (void)n_in; (void)out_size; (void)ws_size;
    const float* feat_moving = (const float*)d_in[0];
    const float* feat_fixed  = (const float*)d_in[1];
    const float* w1  = (const float*)d_in[2];
    const float* b1  = (const float*)d_in[3];
    const float* g1  = (const float*)d_in[4];
    const float* be1 = (const float*)d_in[5];
    const float* w2  = (const float*)d_in[6];
    const float* b2  = (const float*)d_in[7];
    const float* g2  = (const float*)d_in[8];
    const float* be2 = (const float*)d_in[9];
    const float* wsw = (const float*)d_in[10];
    const float* bs  = (const float*)d_in[11];
    const float* gs  = (const float*)d_in[12];
    const float* bes = (const float*)d_in[13];
    const float* wp  = (const float*)d_in[14];
    const float* bp  = (const float*)d_in[15];

    // workspace by lifetime (MiB offsets), max ~160.1 MiB:
    //   featB [0,32)   bf16 [vox][ci]   live tobf_skip..conv1 ; embB aliases
    //   cA    [32,64)  bf16 [co][vox]   live conv1..gn_t
    //   AB    [64,96)  bf16 [vox][ci]   live gn_t..conv2
    //   cB    [96,128) bf16 [co][vox]   live conv2..combine
    //   skipB [128,160)bf16 [vox][co]   live tobf_skip..combine
    //   embB = featB region, bf16 [img][vox][16], live combine..attn
    //   stats[0..47] GN stats; stats[48..63] = 64B zero page for conv staging
    char* base = (char*)d_ws;
    ushort* featB = (ushort*)base;
    ushort* cA    = (ushort*)(base + (32ull << 20));
    ushort* AB    = (ushort*)(base + (64ull << 20));
    ushort* cB    = (ushort*)(base + (96ull << 20));
    ushort* skipB = (ushort*)(base + (128ull << 20));
    ushort* embB  = (ushort*)base;
    float*  stats = (float*)(base + (160ull << 20));
    const ushort* zeroPg = (const ushort*)(stats + 48);
    ushort* wB1   = (ushort*)(stats + 64);
    ushort* wB2   = wB1 + 27648;
    ushort* wsB   = wB2 + 27648;

    prep_kernel<<<108, 256, 0, stream>>>(w1, w2, wsw, wB1, wB2, wsB, stats);
    tobf_skip_kernel<<<dim3(512, 2), 256, 0, stream>>>(feat_fixed, feat_moving, wsB, bs,
                                                       featB, skipB, stats);
    conv3_mfma_kernel<<<dim3(512, 2), 256, 0, stream>>>(featB, wB1, b1, zeroPg, cA, stats, 0);
    gn_transpose_kernel<<<dim3(256, 2), 256, 0, stream>>>(cA, stats, g1, be1, AB);
    conv3_mfma_kernel<<<dim3(512, 2), 256, 0, stream>>>(AB, wB2, b2, zeroPg, cB, stats, 1);
    combine_kernel<<<dim3(1024, 2), 256, 0, stream>>>(cB, skipB, stats, g2, be2, gs, bes,
                                                      wp, bp, embB);
    attn_kernel<<<1024, 256, 0, stream>>>(embB, (float*)d_out);
}